// Round 2
// baseline (74611.334 us; speedup 1.0000x reference)
//
#include <hip/hip_runtime.h>
#include <math.h>

#define KDIM 2560
#define DDIM 512
#define NB 64
#define TS 16

#define QM 2560
#define QN 512
#define PW 16

// out layout (floats): m_cor @0 (2560), l_cor @2560 (2560*2560), u @6556160 (512),
// error @6556672 (512), diffusion @6557184 (1)
#define OUT_LCOR 2560
#define OUT_U    6556160
#define OUT_ERR  6556672
#define OUT_DIFF 6557184

// scal layout (doubles): [0..4]=p_pat, [5..9]=pinv_pat, [10]=diffusion

__global__ void k_setup(const float* dt, double* scal){
  if (threadIdx.x==0 && blockIdx.x==0){
    double adt = fabs((double)dt[0]);
    const double scales[5] = {24.0,6.0,2.0,1.0,1.0};
    for (int i=0;i<5;i++){
      double pw = (double)(4-i)+0.5;
      scal[i]   = pow(adt, pw)/scales[i];
      scal[5+i] = pow(adt,-pw)*scales[i];
    }
  }
}

__global__ void k_mext(const float* a, const float* m0, const double* scal, double* mext){
  int r = blockIdx.x*blockDim.x + threadIdx.x;
  if (r>=KDIM) return;
  int j=r/5, i=r%5;
  const float* arow = a + (size_t)r*KDIM + 5*j;
  const float* m0b  = m0 + 5*j;
  double acc=0;
  for (int l=0;l<5;l++) acc += (double)arow[l]*scal[5+l]*(double)m0b[l];
  mext[r] = scal[i]*acc;
}

__global__ void k_mobs(const float* H, const float* bias, const double* mext, double* mobs){
  __shared__ double red[256];
  int r = blockIdx.x;
  const float* Hr = H + (size_t)r*KDIM;
  double acc=0;
  for (int c=threadIdx.x;c<KDIM;c+=256) acc += (double)Hr[c]*mext[c];
  red[threadIdx.x]=acc; __syncthreads();
  for (int s=128;s>0;s>>=1){ if (threadIdx.x<s) red[threadIdx.x]+=red[threadIdx.x+s]; __syncthreads(); }
  if (threadIdx.x==0) mobs[r] = red[0] - (double)bias[r];
}

// A (col-major QM x QN) = M1 = (H @ (p_inv[:,None]*q)).T in fp64
// A[j*QM + i] = sum_t H[j, 5*bi+t] * pinv[t] * q[5*bi+t, i],  bi=i/5
__global__ void k_A(const float* H, const float* q, const double* scal, double* A){
  int idx = blockIdx.x*blockDim.x+threadIdx.x;
  if (idx >= QN*QM) return;
  int j = idx / QM;
  int i = idx % QM;
  int bi = i/5;
  double acc=0;
  for (int t=0;t<5;t++)
    acc += (double)H[(size_t)j*QM + 5*bi+t]*scal[5+t]*(double)q[(size_t)(5*bi+t)*QM + i];
  A[idx] = acc;
}

// ---- Householder QR (LAPACK sign convention), panel factorization ----
__global__ __launch_bounds__(1024) void qr_panel(double* A, double* beta, double* vhead, int col0){
  __shared__ double vbuf[QM];
  __shared__ double red[1024];
  __shared__ double sh[2];
  int tid = threadIdx.x;
  for (int j=0;j<PW;j++){
    int c = col0 + j;
    double acc = 0;
    for (int r = c + tid; r < QM; r += 1024){
      double v = A[(size_t)c*QM + r];
      vbuf[r-c] = v;
      acc += v*v;
    }
    red[tid] = acc; __syncthreads();
    for (int s=512; s>0; s>>=1){ if (tid<s) red[tid]+=red[tid+s]; __syncthreads(); }
    if (tid==0){
      double s0 = red[0];
      double x1 = vbuf[0];
      double nrm = sqrt(s0);
      double alpha = (x1 >= 0.0) ? -nrm : nrm;   // LAPACK: R_cc = -sign(x1)*||x||
      double v1 = x1 - alpha;
      double vtv = s0 - 2.0*alpha*x1 + alpha*alpha;
      double b = (vtv > 0.0) ? 2.0/vtv : 0.0;
      vbuf[0] = v1;
      sh[0] = b;
      A[(size_t)c*QM + c] = alpha;
      beta[c] = b;
      vhead[c] = v1;
    }
    __syncthreads();
    double b = sh[0];
    int wid = tid >> 6, lane = tid & 63;
    int jj = j + 1 + wid;
    if (jj < PW && b != 0.0){
      int cc = col0 + jj;
      double d = 0;
      for (int r = c + lane; r < QM; r += 64)
        d += vbuf[r-c]*A[(size_t)cc*QM + r];
      #pragma unroll
      for (int off=32; off>0; off>>=1) d += __shfl_down(d, off);
      d = __shfl(d, 0);
      double sc = b*d;
      for (int r = c + lane; r < QM; r += 64)
        A[(size_t)cc*QM + r] -= sc*vbuf[r-c];
    }
    __syncthreads();
  }
}

// compute V^T V (needed pairs) and build compact-WY T (upper) for the panel
__global__ __launch_bounds__(512) void qr_vtvT(const double* A, const double* beta, const double* vhead,
                                               int col0, double* Tbuf){
  __shared__ double VtV[PW][PW];
  __shared__ double T[PW][PW];
  int tid = threadIdx.x, wid = tid>>6, lane = tid&63;
  for (int p = wid; p < PW*(PW-1)/2; p += 8){
    int i=0,j=1,cnt=p;
    for (j=1;j<PW;j++){ if (cnt < j){ i = cnt; break; } cnt -= j; }
    int ci = col0+i, cj = col0+j;
    double d=0;
    for (int r = cj + lane; r < QM; r += 64){
      double vi = A[(size_t)ci*QM + r];
      double vj = (r==cj) ? vhead[cj] : A[(size_t)cj*QM + r];
      d += vi*vj;
    }
    #pragma unroll
    for (int off=32;off>0;off>>=1) d += __shfl_down(d,off);
    if (lane==0) VtV[i][j]=d;
  }
  __syncthreads();
  if (tid==0){
    for (int j=0;j<PW;j++){
      double bj = beta[col0+j];
      T[j][j] = bj;
      for (int i=0;i<j;i++){
        double z=0;
        for (int t=i;t<j;t++) z += T[i][t]*VtV[t][j];
        T[i][j] = -bj*z;
      }
    }
    for (int i=0;i<PW;i++) for (int j2=0;j2<PW;j2++)
      Tbuf[i*PW+j2] = (j2>=i)? T[i][j2] : 0.0;
  }
}

// W2[cc] = T^T (V^T a_cc) for all trailing columns
__global__ __launch_bounds__(256) void qr_w1(const double* A, const double* vhead, const double* Tbuf,
                                             int col0, double* W2){
  __shared__ double red[256][PW];
  int cc = col0 + PW + blockIdx.x;
  int tid = threadIdx.x;
  double acc[PW];
  #pragma unroll
  for (int j=0;j<PW;j++) acc[j]=0;
  for (int r = col0 + tid; r < QM; r += 256){
    double aval = A[(size_t)cc*QM + r];
    #pragma unroll
    for (int j=0;j<PW;j++){
      int cj = col0 + j;
      double vj = (r > cj) ? A[(size_t)cj*QM + r] : ((r==cj)? vhead[cj] : 0.0);
      acc[j] += vj*aval;
    }
  }
  #pragma unroll
  for (int j=0;j<PW;j++) red[tid][j]=acc[j];
  __syncthreads();
  for (int s=128;s>0;s>>=1){
    if (tid<s){ for (int j=0;j<PW;j++) red[tid][j]+=red[tid+s][j]; }
    __syncthreads();
  }
  if (tid < PW){
    double s=0;
    for (int j=0;j<=tid;j++) s += Tbuf[j*PW+tid]*red[0][j];
    W2[(size_t)cc*PW + tid] = s;
  }
}

// A_trail -= V * W2
__global__ __launch_bounds__(256) void qr_apply(double* A, const double* vhead, const double* W2, int col0){
  __shared__ double w2[PW];
  int cc = col0 + PW + blockIdx.x;
  if (threadIdx.x < PW) w2[threadIdx.x] = W2[(size_t)cc*PW + threadIdx.x];
  __syncthreads();
  int r = col0 + blockIdx.y*256 + threadIdx.x;
  if (r >= QM) return;
  double s=0;
  #pragma unroll
  for (int j=0;j<PW;j++){
    int cj = col0+j;
    double vj = (r > cj) ? A[(size_t)cj*QM + r] : ((r==cj)? vhead[cj] : 0.0);
    s += vj*w2[j];
  }
  A[(size_t)cc*QM + r] -= s;
}

__global__ void k_extractR(const double* A, double* Rq){
  int idx = blockIdx.x*blockDim.x+threadIdx.x;
  if (idx >= QN*QN) return;
  int r = idx/QN, c = idx%QN;
  Rq[idx] = (r<=c) ? A[(size_t)c*QM + r] : 0.0;
}

__global__ void k_colnorm(const double* Rq, double* g1d){
  int c = blockIdx.x*blockDim.x+threadIdx.x;
  if (c>=QN) return;
  double s=0;
  for (int r=0;r<=c;r++){ double v=Rq[(size_t)r*QN+c]; s+=v*v; }
  g1d[c]=s;
}

// X = a @ (p_inv[:,None]*l0)
__global__ void k_X(const float* a, const float* l0, const double* scal, float* X){
  int idx=blockIdx.x*blockDim.x+threadIdx.x;
  if (idx>=KDIM*KDIM) return;
  int r=idx/KDIM, c=idx%KDIM;
  int j=r/5;
  const float* arow = a + (size_t)r*KDIM + 5*j;
  double acc=0;
  for (int l=0;l<5;l++)
    acc += (double)arow[l]*scal[5+l]*(double)l0[(size_t)(5*j+l)*KDIM+c];
  X[idx]=(float)acc;
}

template<typename TA,typename TB,typename TC>
__global__ void gemm_nt(const TA* A,const TB* B,TC* C,int M,int N,int Kc){
  __shared__ double As[TS][TS+1], Bs[TS][TS+1];
  int tx=threadIdx.x, ty=threadIdx.y;
  int m=blockIdx.y*TS+ty, n=blockIdx.x*TS+tx;
  int bn=blockIdx.x*TS+ty;
  double acc=0;
  for (int k0=0;k0<Kc;k0+=TS){
    As[ty][tx] = (m<M) ? (double)A[(size_t)m*Kc+k0+tx] : 0.0;
    Bs[ty][tx] = (bn<N)? (double)B[(size_t)bn*Kc+k0+tx] : 0.0;
    __syncthreads();
    #pragma unroll
    for (int t=0;t<TS;t++) acc += As[ty][t]*Bs[tx][t];
    __syncthreads();
  }
  if (m<M && n<N) C[(size_t)m*N+n]=(TC)acc;
}

template<typename TA,typename TB,typename TC>
__global__ void gemm_nn(const TA* A,const TB* B,TC* C,int M,int N,int Kc){
  __shared__ double As[TS][TS+1], Bs[TS][TS+1];
  int tx=threadIdx.x, ty=threadIdx.y;
  int m=blockIdx.y*TS+ty, n=blockIdx.x*TS+tx;
  double acc=0;
  for (int k0=0;k0<Kc;k0+=TS){
    As[ty][tx] = (m<M)?(double)A[(size_t)m*Kc+k0+tx]:0.0;
    Bs[ty][tx] = (n<N)?(double)B[(size_t)(k0+ty)*N+n]:0.0;
    __syncthreads();
    #pragma unroll
    for (int t=0;t<TS;t++) acc += As[ty][t]*Bs[t][tx];
    __syncthreads();
  }
  if (m<M&&n<N) C[(size_t)m*N+n]=(TC)acc;
}

__global__ void syrk_lower(const float* X, double* G, int n){
  int R0=blockIdx.y*TS, S0=blockIdx.x*TS;
  if (S0>R0) return;
  __shared__ double As[TS][TS+1], Bs[TS][TS+1];
  int tx=threadIdx.x, ty=threadIdx.y;
  int kend = S0+2*TS; if (kend>n) kend=n;
  double acc=0;
  for (int k0=0;k0<kend;k0+=TS){
    As[ty][tx]=(double)X[(size_t)(R0+ty)*n+k0+tx];
    Bs[ty][tx]=(double)X[(size_t)(S0+ty)*n+k0+tx];
    __syncthreads();
    #pragma unroll
    for (int t=0;t<TS;t++) acc+=As[ty][t]*Bs[tx][t];
    __syncthreads();
  }
  G[(size_t)(R0+ty)*n+S0+tx]=acc;
}

__global__ void k_addqqt(const float* q, const double* scal, double* G2){
  int idx=blockIdx.x*blockDim.x+threadIdx.x;
  if (idx>=DDIM*15) return;
  int j=idx/15, t=idx%15;
  int i=0; while (t >= i+1){ t-=i+1; i++; }
  int jj=t;
  double acc=0;
  for (int k=0;k<5;k++) acc += (double)q[(size_t)i*KDIM+k]*(double)q[(size_t)jj*KDIM+k];
  double dd=scal[10]*scal[10];
  G2[(size_t)(5*j+i)*KDIM + 5*j+jj] += dd*acc;
}

__global__ void chol_diag(double* A, int n, int k0){
  __shared__ double piv;
  int tid=threadIdx.x;
  for (int j=0;j<NB;j++){
    size_t gj=(size_t)(k0+j);
    __syncthreads();
    if (tid==0){ double v=A[gj*n+gj]; piv=sqrt(fmax(v,1e-280)); A[gj*n+gj]=piv; }
    __syncthreads();
    double pv=piv;
    for (int r=j+1+tid;r<NB;r+=blockDim.x) A[(size_t)(k0+r)*n+gj] /= pv;
    __syncthreads();
    for (int c=j+1;c<NB;c++){
      double lc=A[(size_t)(k0+c)*n+gj];
      for (int r=c+tid;r<NB;r+=blockDim.x)
        A[(size_t)(k0+r)*n+(size_t)(k0+c)] -= A[(size_t)(k0+r)*n+gj]*lc;
    }
  }
}

__global__ void chol_trsm(double* A,int n,int k0){
  int r=k0+NB+blockIdx.x*blockDim.x+threadIdx.x;
  if (r>=n) return;
  double* Ar=A+(size_t)r*n;
  for (int j=0;j<NB;j++){
    const double* Lj=A+(size_t)(k0+j)*n+k0;
    double s=Ar[k0+j];
    for (int t=0;t<j;t++) s-=Ar[k0+t]*Lj[t];
    Ar[k0+j]=s/Lj[j];
  }
}

__global__ void chol_syrk(double* A,int n,int k0){
  int ts0=k0+NB;
  int R0=ts0+blockIdx.y*TS, S0=ts0+blockIdx.x*TS;
  if (S0>R0) return;
  __shared__ double Ap[TS][NB+1], Bp[TS][NB+1];
  int lin = threadIdx.y*TS+threadIdx.x;
  for (int e=lin; e<TS*NB; e+=256){
    int rr=e/NB, cc=e%NB;
    Ap[rr][cc]=A[(size_t)(R0+rr)*n+k0+cc];
    Bp[rr][cc]=A[(size_t)(S0+rr)*n+k0+cc];
  }
  __syncthreads();
  double acc=0;
  #pragma unroll 8
  for (int t=0;t<NB;t++) acc += Ap[threadIdx.y][t]*Bp[threadIdx.x][t];
  A[(size_t)(R0+threadIdx.y)*n + (S0+threadIdx.x)] -= acc;
}

// solve R x = m_obs (R upper, LAPACK-signed), diffusion + error
__global__ void k_resw(const double* Rq, const double* mobs, const double* g1d,
                       double* scal, float* out){
  __shared__ double b[DDIM];
  __shared__ double x[DDIM];
  __shared__ double red[DDIM];
  int tid=threadIdx.x;
  b[tid]=mobs[tid];
  __syncthreads();
  for (int k=DDIM-1;k>=0;k--){
    if (tid==0) x[k]=b[k]/Rq[(size_t)k*DDIM+k];
    __syncthreads();
    if (tid<k) b[tid] -= Rq[(size_t)tid*DDIM+k]*x[k];
    __syncthreads();
  }
  red[tid]=x[tid]*x[tid]; __syncthreads();
  for (int s=DDIM/2;s>0;s>>=1){ if (tid<s) red[tid]+=red[tid+s]; __syncthreads(); }
  double diff=sqrt(red[0]/(double)DDIM);
  if (tid==0){ scal[10]=diff; out[OUT_DIFF]=(float)diff; }
  out[OUT_ERR+tid]=(float)(diff*sqrt(fmax(g1d[tid],0.0)));
}

__global__ void k_extract(const double* G2, const double* scal, float* lext){
  int idx=blockIdx.x*blockDim.x+threadIdx.x;
  if (idx>=KDIM*KDIM) return;
  int r=idx/KDIM, c=idx%KDIM;
  double v = (c<=r)? scal[r%5]*G2[idx] : 0.0;
  lext[idx]=(float)v;
}

__global__ void k_trinv(const double* L, double* T, int n){
  int j=blockIdx.x*blockDim.x+threadIdx.x;
  if (j>=n) return;
  for (int r=0;r<j;r++) T[(size_t)r*n+j]=0.0;
  for (int r=j;r<n;r++){
    const double* Lr=L+(size_t)r*n;
    double s=(r==j)?1.0:0.0;
    for (int t=j;t<r;t++) s-=Lr[t]*T[(size_t)t*n+j];
    T[(size_t)r*n+j]=s/Lr[r];
  }
}

__global__ void k_transpose(const double* T, double* W, int n){
  int i=blockIdx.y*TS+threadIdx.y, j=blockIdx.x*TS+threadIdx.x;
  if (i<n&&j<n) W[(size_t)i*n+j]=T[(size_t)j*n+i];
}

__global__ void k_mcor(const float* gain, const double* mobs, const double* mext, float* out){
  int r=blockIdx.x*blockDim.x+threadIdx.x;
  if (r>=KDIM) return;
  const float* gr = gain + (size_t)r*DDIM;
  double acc=0;
  for (int s=0;s<DDIM;s++) acc += (double)gr[s]*mobs[s];
  double mc = mext[r]-acc;
  out[r]=(float)mc;
  if (r%5==0) out[OUT_U + r/5]=(float)mc;
}

__global__ void k_lcor(const float* gain, const float* lobs, const float* lext, float* out){
  __shared__ double As[TS][TS+1], Bs[TS][TS+1];
  int tx=threadIdx.x, ty=threadIdx.y;
  int m=blockIdx.y*TS+ty, n=blockIdx.x*TS+tx;
  double acc=0;
  for (int k0=0;k0<DDIM;k0+=TS){
    As[ty][tx]=(double)gain[(size_t)m*DDIM+k0+tx];
    Bs[ty][tx]=(double)lobs[(size_t)(k0+ty)*KDIM+n];
    __syncthreads();
    #pragma unroll
    for (int t=0;t<TS;t++) acc+=As[ty][t]*Bs[t][tx];
    __syncthreads();
  }
  out[OUT_LCOR + (size_t)m*KDIM+n] = (float)((double)lext[(size_t)m*KDIM+n]-acc);
}

static void chol_blocked(double* A, int n, hipStream_t stream){
  for (int k0=0;k0<n;k0+=NB){
    chol_diag<<<1,256,0,stream>>>(A,n,k0);
    int m = n-k0-NB;
    if (m>0){
      chol_trsm<<<(m+255)/256,256,0,stream>>>(A,n,k0);
      chol_syrk<<<dim3(m/TS,m/TS),dim3(TS,TS),0,stream>>>(A,n,k0);
    }
  }
}

extern "C" void kernel_launch(void* const* d_in, const int* in_sizes, int n_in,
                              void* d_out, int out_size, void* d_ws, size_t ws_size,
                              hipStream_t stream) {
  const float* m0  = (const float*)d_in[0];
  const float* l0  = (const float*)d_in[1];
  const float* H   = (const float*)d_in[2];
  const float* bias= (const float*)d_in[3];
  const float* dt  = (const float*)d_in[4];
  const float* a   = (const float*)d_in[5];
  const float* q   = (const float*)d_in[6];
  float* out = (float*)d_out;

  char* w=(char*)d_ws;
  auto alloc=[&](size_t bytes)->char*{ char* p=w; w += ((bytes+255)/256)*256; return p; };
  double* scal =(double*)alloc(16*8);
  double* mext =(double*)alloc((size_t)KDIM*8);
  double* mobs =(double*)alloc((size_t)DDIM*8);
  double* g1d  =(double*)alloc((size_t)DDIM*8);
  double* betaA=(double*)alloc((size_t)QN*8);
  double* vheadA=(double*)alloc((size_t)QN*8);
  double* Tbuf =(double*)alloc((size_t)PW*PW*8);
  double* W2   =(double*)alloc((size_t)QN*PW*8);
  double* Aq   =(double*)alloc((size_t)QM*QN*8);     // QR working matrix (fp64)
  double* Rq   =(double*)alloc((size_t)QN*QN*8);     // R factor
  double* S    =(double*)alloc((size_t)DDIM*DDIM*8); // innovation Gram + chol
  double* G2   =(double*)alloc((size_t)KDIM*KDIM*8); // big Gram -> chol; region reused
  float*  LOBS =(float*) alloc((size_t)DDIM*KDIM*4);
  float*  X    =(float*) alloc((size_t)KDIM*KDIM*4); // X; later l_ext
  double* TINV = (double*)G2;
  double* Wt   = TINV + (size_t)DDIM*DDIM;
  double* SINV = Wt   + (size_t)DDIM*DDIM;
  float*  CC   = (float*)(SINV + (size_t)DDIM*DDIM);
  float*  GAIN = CC + (size_t)KDIM*DDIM;
  float*  LEXT = X;

  dim3 t16(TS,TS);

  // ---- extrapolate mean, observe ----
  k_setup<<<1,1,0,stream>>>(dt, scal);
  k_mext<<<(KDIM+255)/256,256,0,stream>>>(a, m0, scal, mext);
  k_mobs<<<DDIM,256,0,stream>>>(H, bias, mext, mobs);

  // ---- first QR: Householder fp64 with LAPACK signs ----
  k_A<<<(QN*QM+255)/256,256,0,stream>>>(H, q, scal, Aq);
  for (int p=0;p<QN/PW;p++){
    int col0=p*PW;
    qr_panel<<<1,1024,0,stream>>>(Aq, betaA, vheadA, col0);
    int ntr = QN - col0 - PW;
    if (ntr>0){
      qr_vtvT<<<1,512,0,stream>>>(Aq,betaA,vheadA,col0,Tbuf);
      int rowchunks = (QM - col0 + 255)/256;
      qr_w1<<<ntr,256,0,stream>>>(Aq,vheadA,Tbuf,col0,W2);
      qr_apply<<<dim3(ntr,rowchunks),256,0,stream>>>(Aq,vheadA,W2,col0);
    }
  }
  k_extractR<<<(QN*QN+255)/256,256,0,stream>>>(Aq, Rq);
  k_colnorm<<<(QN+255)/256,256,0,stream>>>(Rq, g1d);
  k_resw<<<1,DDIM,0,stream>>>(Rq, mobs, g1d, scal, out);

  // ---- extrapolated covariance sqrt via Gram + Cholesky ----
  k_X<<<(KDIM*KDIM+255)/256,256,0,stream>>>(a, l0, scal, X);
  syrk_lower<<<dim3(KDIM/TS,KDIM/TS),t16,0,stream>>>(X, G2, KDIM);
  k_addqqt<<<(DDIM*15+255)/256,256,0,stream>>>(q, scal, G2);
  chol_blocked(G2, KDIM, stream);
  k_extract<<<(KDIM*KDIM+255)/256,256,0,stream>>>(G2, scal, LEXT);

  // ---- correction ----
  gemm_nn<float,float,float><<<dim3(KDIM/TS,DDIM/TS),t16,0,stream>>>(H, LEXT, LOBS, DDIM, KDIM, KDIM);
  gemm_nt<float,float,double><<<dim3(DDIM/TS,DDIM/TS),t16,0,stream>>>(LOBS,LOBS,S,DDIM,DDIM,KDIM);
  chol_blocked(S, DDIM, stream);
  k_trinv<<<(DDIM+255)/256,256,0,stream>>>(S, TINV, DDIM);
  k_transpose<<<dim3(DDIM/TS,DDIM/TS),t16,0,stream>>>(TINV, Wt, DDIM);
  gemm_nt<double,double,double><<<dim3(DDIM/TS,DDIM/TS),t16,0,stream>>>(Wt,Wt,SINV,DDIM,DDIM,DDIM);
  gemm_nt<float,float,float><<<dim3(DDIM/TS,KDIM/TS),t16,0,stream>>>(LEXT,LOBS,CC,KDIM,DDIM,KDIM);
  gemm_nn<float,double,float><<<dim3(DDIM/TS,KDIM/TS),t16,0,stream>>>(CC,SINV,GAIN,KDIM,DDIM,DDIM);

  k_mcor<<<(KDIM+255)/256,256,0,stream>>>(GAIN, mobs, mext, out);
  k_lcor<<<dim3(KDIM/TS,KDIM/TS),t16,0,stream>>>(GAIN, LOBS, LEXT, out);
}

// Round 3
// 18854.367 us; speedup vs baseline: 3.9572x; 3.9572x over previous
//
#include <hip/hip_runtime.h>
#include <math.h>

#define KDIM 2560
#define DDIM 512
#define NB 64
#define TS 16
#define GBM 32
#define GBK 16

#define QM 2560
#define QN 512
#define PW 16

// out layout (floats): m_cor @0 (2560), l_cor @2560 (2560*2560), u @6556160 (512),
// error @6556672 (512), diffusion @6557184 (1)
#define OUT_LCOR 2560
#define OUT_U    6556160
#define OUT_ERR  6556672
#define OUT_DIFF 6557184

// scal layout (doubles): [0..4]=p_pat, [5..9]=pinv_pat, [10]=diffusion

__global__ void k_setup(const float* dt, double* scal){
  if (threadIdx.x==0 && blockIdx.x==0){
    double adt = fabs((double)dt[0]);
    const double scales[5] = {24.0,6.0,2.0,1.0,1.0};
    for (int i=0;i<5;i++){
      double pw = (double)(4-i)+0.5;
      scal[i]   = pow(adt, pw)/scales[i];
      scal[5+i] = pow(adt,-pw)*scales[i];
    }
  }
}

__global__ void k_mext(const float* a, const float* m0, const double* scal, double* mext){
  int r = blockIdx.x*blockDim.x + threadIdx.x;
  if (r>=KDIM) return;
  int j=r/5, i=r%5;
  const float* arow = a + (size_t)r*KDIM + 5*j;
  const float* m0b  = m0 + 5*j;
  double acc=0;
  for (int l=0;l<5;l++) acc += (double)arow[l]*scal[5+l]*(double)m0b[l];
  mext[r] = scal[i]*acc;
}

__global__ void k_mobs(const float* H, const float* bias, const double* mext, double* mobs){
  __shared__ double red[256];
  int r = blockIdx.x;
  const float* Hr = H + (size_t)r*KDIM;
  double acc=0;
  for (int c=threadIdx.x;c<KDIM;c+=256) acc += (double)Hr[c]*mext[c];
  red[threadIdx.x]=acc; __syncthreads();
  for (int s=128;s>0;s>>=1){ if (threadIdx.x<s) red[threadIdx.x]+=red[threadIdx.x+s]; __syncthreads(); }
  if (threadIdx.x==0) mobs[r] = red[0] - (double)bias[r];
}

// A (col-major QM x QN) = (H @ (p_inv[:,None]*q)).T in fp64
__global__ void k_A(const float* H, const float* q, const double* scal, double* A){
  int idx = blockIdx.x*blockDim.x+threadIdx.x;
  if (idx >= QN*QM) return;
  int j = idx / QM;
  int i = idx % QM;
  int bi = i/5;
  double acc=0;
  for (int t=0;t<5;t++)
    acc += (double)H[(size_t)j*QM + 5*bi+t]*scal[5+t]*(double)q[(size_t)(5*bi+t)*QM + i];
  A[idx] = acc;
}

// ---- Householder QR (LAPACK sign convention) ----
__global__ __launch_bounds__(1024) void qr_panel(double* A, double* beta, double* vhead, int col0){
  __shared__ double vbuf[QM];
  __shared__ double red[1024];
  __shared__ double sh[2];
  int tid = threadIdx.x;
  for (int j=0;j<PW;j++){
    int c = col0 + j;
    double acc = 0;
    for (int r = c + tid; r < QM; r += 1024){
      double v = A[(size_t)c*QM + r];
      vbuf[r-c] = v;
      acc += v*v;
    }
    red[tid] = acc; __syncthreads();
    for (int s=512; s>0; s>>=1){ if (tid<s) red[tid]+=red[tid+s]; __syncthreads(); }
    if (tid==0){
      double s0 = red[0];
      double x1 = vbuf[0];
      double nrm = sqrt(s0);
      double alpha = (x1 >= 0.0) ? -nrm : nrm;
      double v1 = x1 - alpha;
      double vtv = s0 - 2.0*alpha*x1 + alpha*alpha;
      double b = (vtv > 0.0) ? 2.0/vtv : 0.0;
      vbuf[0] = v1;
      sh[0] = b;
      A[(size_t)c*QM + c] = alpha;
      beta[c] = b;
      vhead[c] = v1;
    }
    __syncthreads();
    double b = sh[0];
    int wid = tid >> 6, lane = tid & 63;
    int jj = j + 1 + wid;
    if (jj < PW && b != 0.0){
      int cc = col0 + jj;
      double d = 0;
      for (int r = c + lane; r < QM; r += 64)
        d += vbuf[r-c]*A[(size_t)cc*QM + r];
      #pragma unroll
      for (int off=32; off>0; off>>=1) d += __shfl_down(d, off);
      d = __shfl(d, 0);
      double sc = b*d;
      for (int r = c + lane; r < QM; r += 64)
        A[(size_t)cc*QM + r] -= sc*vbuf[r-c];
    }
    __syncthreads();
  }
}

__global__ __launch_bounds__(512) void qr_vtvT(const double* A, const double* beta, const double* vhead,
                                               int col0, double* Tbuf){
  __shared__ double VtV[PW][PW];
  __shared__ double T[PW][PW];
  int tid = threadIdx.x, wid = tid>>6, lane = tid&63;
  for (int p = wid; p < PW*(PW-1)/2; p += 8){
    int i=0,j=1,cnt=p;
    for (j=1;j<PW;j++){ if (cnt < j){ i = cnt; break; } cnt -= j; }
    int ci = col0+i, cj = col0+j;
    double d=0;
    for (int r = cj + lane; r < QM; r += 64){
      double vi = A[(size_t)ci*QM + r];
      double vj = (r==cj) ? vhead[cj] : A[(size_t)cj*QM + r];
      d += vi*vj;
    }
    #pragma unroll
    for (int off=32;off>0;off>>=1) d += __shfl_down(d,off);
    if (lane==0) VtV[i][j]=d;
  }
  __syncthreads();
  if (tid==0){
    for (int j=0;j<PW;j++){
      double bj = beta[col0+j];
      T[j][j] = bj;
      for (int i=0;i<j;i++){
        double z=0;
        for (int t=i;t<j;t++) z += T[i][t]*VtV[t][j];
        T[i][j] = -bj*z;
      }
    }
    for (int i=0;i<PW;i++) for (int j2=0;j2<PW;j2++)
      Tbuf[i*PW+j2] = (j2>=i)? T[i][j2] : 0.0;
  }
}

__global__ __launch_bounds__(256) void qr_w1(const double* A, const double* vhead, const double* Tbuf,
                                             int col0, double* W2){
  __shared__ double red[256][PW];
  int cc = col0 + PW + blockIdx.x;
  int tid = threadIdx.x;
  double acc[PW];
  #pragma unroll
  for (int j=0;j<PW;j++) acc[j]=0;
  for (int r = col0 + tid; r < QM; r += 256){
    double aval = A[(size_t)cc*QM + r];
    #pragma unroll
    for (int j=0;j<PW;j++){
      int cj = col0 + j;
      double vj = (r > cj) ? A[(size_t)cj*QM + r] : ((r==cj)? vhead[cj] : 0.0);
      acc[j] += vj*aval;
    }
  }
  #pragma unroll
  for (int j=0;j<PW;j++) red[tid][j]=acc[j];
  __syncthreads();
  for (int s=128;s>0;s>>=1){
    if (tid<s){ for (int j=0;j<PW;j++) red[tid][j]+=red[tid+s][j]; }
    __syncthreads();
  }
  if (tid < PW){
    double s=0;
    for (int j=0;j<=tid;j++) s += Tbuf[j*PW+tid]*red[0][j];
    W2[(size_t)cc*PW + tid] = s;
  }
}

__global__ __launch_bounds__(256) void qr_apply(double* A, const double* vhead, const double* W2, int col0){
  __shared__ double w2[PW];
  int cc = col0 + PW + blockIdx.x;
  if (threadIdx.x < PW) w2[threadIdx.x] = W2[(size_t)cc*PW + threadIdx.x];
  __syncthreads();
  int r = col0 + blockIdx.y*256 + threadIdx.x;
  if (r >= QM) return;
  double s=0;
  #pragma unroll
  for (int j=0;j<PW;j++){
    int cj = col0+j;
    double vj = (r > cj) ? A[(size_t)cj*QM + r] : ((r==cj)? vhead[cj] : 0.0);
    s += vj*w2[j];
  }
  A[(size_t)cc*QM + r] -= s;
}

__global__ void k_extractR(const double* A, double* Rq){
  int idx = blockIdx.x*blockDim.x+threadIdx.x;
  if (idx >= QN*QN) return;
  int r = idx/QN, c = idx%QN;
  Rq[idx] = (r<=c) ? A[(size_t)c*QM + r] : 0.0;
}

__global__ void k_colnorm(const double* Rq, double* g1d){
  int c = blockIdx.x*blockDim.x+threadIdx.x;
  if (c>=QN) return;
  double s=0;
  for (int r=0;r<=c;r++){ double v=Rq[(size_t)r*QN+c]; s+=v*v; }
  g1d[c]=s;
}

// solve R x = m_obs (R upper, LAPACK-signed), diffusion + error
__global__ void k_resw(const double* Rq, const double* mobs, const double* g1d,
                       double* scal, float* out){
  __shared__ double b[DDIM];
  __shared__ double x[DDIM];
  __shared__ double red[DDIM];
  int tid=threadIdx.x;
  b[tid]=mobs[tid];
  __syncthreads();
  for (int k=DDIM-1;k>=0;k--){
    if (tid==0) x[k]=b[k]/Rq[(size_t)k*DDIM+k];
    __syncthreads();
    if (tid<k) b[tid] -= Rq[(size_t)tid*DDIM+k]*x[k];
    __syncthreads();
  }
  red[tid]=x[tid]*x[tid]; __syncthreads();
  for (int s=DDIM/2;s>0;s>>=1){ if (tid<s) red[tid]+=red[tid+s]; __syncthreads(); }
  double diff=sqrt(red[0]/(double)DDIM);
  if (tid==0){ scal[10]=diff; out[OUT_DIFF]=(float)diff; }
  out[OUT_ERR+tid]=(float)(diff*sqrt(fmax(g1d[tid],0.0)));
}

// X = a @ (p_inv[:,None]*l0)
__global__ void k_X(const float* a, const float* l0, const double* scal, float* X){
  int idx=blockIdx.x*blockDim.x+threadIdx.x;
  if (idx>=KDIM*KDIM) return;
  int r=idx/KDIM, c=idx%KDIM;
  int j=r/5;
  const float* arow = a + (size_t)r*KDIM + 5*j;
  double acc=0;
  for (int l=0;l<5;l++)
    acc += (double)arow[l]*scal[5+l]*(double)l0[(size_t)(5*j+l)*KDIM+c];
  X[idx]=(float)acc;
}

// G (lower tiles) = X X^T; X[r,c]=0 for c > 5*(r/5)+4 -> k < S0+36
__global__ __launch_bounds__(256) void syrk_lower(const float* __restrict__ X, double* __restrict__ G, int n){
  int R0=blockIdx.y*GBM, S0=blockIdx.x*GBM;
  if (S0>R0) return;
  __shared__ float As[GBM][GBK+1], Bs[GBM][GBK+1];
  int tx=threadIdx.x, ty=threadIdx.y;
  int lin=ty*16+tx;
  double a00=0,a01=0,a10=0,a11=0;
  int kend = S0+GBM+16; if (kend>n) kend=n;
  for (int k0=0;k0<kend;k0+=GBK){
    for (int e=lin;e<GBM*GBK;e+=256){
      int r=e/GBK,k=e%GBK;
      As[r][k]=X[(size_t)(R0+r)*n+k0+k];
      Bs[r][k]=X[(size_t)(S0+r)*n+k0+k];
    }
    __syncthreads();
    #pragma unroll
    for (int t=0;t<GBK;t++){
      double av0=As[2*ty][t], av1=As[2*ty+1][t];
      double bv0=Bs[2*tx][t], bv1=Bs[2*tx+1][t];
      a00+=av0*bv0; a01+=av0*bv1; a10+=av1*bv0; a11+=av1*bv1;
    }
    __syncthreads();
  }
  G[(size_t)(R0+2*ty)*n + S0+2*tx]   = a00;
  G[(size_t)(R0+2*ty)*n + S0+2*tx+1] = a01;
  G[(size_t)(R0+2*ty+1)*n + S0+2*tx]   = a10;
  G[(size_t)(R0+2*ty+1)*n + S0+2*tx+1] = a11;
}

__global__ void k_addqqt(const float* q, const double* scal, double* G2){
  int idx=blockIdx.x*blockDim.x+threadIdx.x;
  if (idx>=DDIM*15) return;
  int j=idx/15, t=idx%15;
  int i=0; while (t >= i+1){ t-=i+1; i++; }
  int jj=t;
  double acc=0;
  for (int k=0;k<5;k++) acc += (double)q[(size_t)i*KDIM+k]*(double)q[(size_t)jj*KDIM+k];
  double dd=scal[10]*scal[10];
  G2[(size_t)(5*j+i)*KDIM + 5*j+jj] += dd*acc;
}

// ---- blocked Cholesky: LDS-resident diagonal factor ----
__global__ __launch_bounds__(256) void chol_diag(double* A, int n, int k0){
  __shared__ double P[NB][NB+1];
  int lin=threadIdx.x;
  for (int e=lin;e<NB*NB;e+=256){int r=e/NB,c=e%NB;P[r][c]=A[(size_t)(k0+r)*n+k0+c];}
  __syncthreads();
  for (int j=0;j<NB;j++){
    if (lin==0) P[j][j]=sqrt(fmax(P[j][j],1e-280));
    __syncthreads();
    double pj=P[j][j];
    for (int r=j+1+lin;r<NB;r+=256) P[r][j]/=pj;
    __syncthreads();
    int w=NB-1-j;
    for (int e=lin;e<w*w;e+=256){
      int rr=e/w, cc=e%w;
      int r=j+1+rr, c=j+1+cc;
      if (c<=r) P[r][c] -= P[r][j]*P[c][j];
    }
    __syncthreads();
  }
  for (int e=lin;e<NB*NB;e+=256){int r=e/NB,c=e%NB;A[(size_t)(k0+r)*n+k0+c]=P[r][c];}
}

// rows below panel: Ar = Ar * Lbb^{-T}, row in registers, Lbb in LDS
__global__ __launch_bounds__(256) void chol_trsm(double* A,int n,int k0){
  __shared__ double Ls[NB][NB+1];
  __shared__ double rec[NB];
  int lin=threadIdx.x;
  for (int e=lin;e<NB*NB;e+=256){int r=e/NB,c=e%NB;Ls[r][c]=A[(size_t)(k0+r)*n+k0+c];}
  __syncthreads();
  if (lin<NB) rec[lin]=1.0/Ls[lin][lin];
  __syncthreads();
  int row = k0+NB + blockIdx.x*256 + lin;
  if (row>=n) return;
  double* Ar = A + (size_t)row*n + k0;
  double ar[NB];
  #pragma unroll
  for (int j=0;j<NB;j++) ar[j]=Ar[j];
  #pragma unroll
  for (int j=0;j<NB;j++){
    double s=ar[j];
    #pragma unroll
    for (int t=0;t<j;t++) s -= ar[t]*Ls[j][t];
    ar[j]=s*rec[j];
  }
  #pragma unroll
  for (int j=0;j<NB;j++) Ar[j]=ar[j];
}

__global__ void chol_syrk(double* A,int n,int k0){
  int ts0=k0+NB;
  int R0=ts0+blockIdx.y*TS, S0=ts0+blockIdx.x*TS;
  if (S0>R0) return;
  __shared__ double Ap[TS][NB+1], Bp[TS][NB+1];
  int lin = threadIdx.y*TS+threadIdx.x;
  for (int e=lin; e<TS*NB; e+=256){
    int rr=e/NB, cc=e%NB;
    Ap[rr][cc]=A[(size_t)(R0+rr)*n+k0+cc];
    Bp[rr][cc]=A[(size_t)(S0+rr)*n+k0+cc];
  }
  __syncthreads();
  double acc=0;
  #pragma unroll 8
  for (int t=0;t<NB;t++) acc += Ap[threadIdx.y][t]*Bp[threadIdx.x][t];
  A[(size_t)(R0+threadIdx.y)*n + (S0+threadIdx.x)] -= acc;
}

static void chol_blocked(double* A, int n, hipStream_t stream){
  for (int k0=0;k0<n;k0+=NB){
    chol_diag<<<1,256,0,stream>>>(A,n,k0);
    int m = n-k0-NB;
    if (m>0){
      chol_trsm<<<(m+255)/256,256,0,stream>>>(A,n,k0);
      chol_syrk<<<dim3(m/TS,m/TS),dim3(TS,TS),0,stream>>>(A,n,k0);
    }
  }
}

// l_ext (f32) = p[:,None] * chol(G2), zero strict upper
__global__ void k_extract(const double* G2, const double* scal, float* lext){
  int idx=blockIdx.x*blockDim.x+threadIdx.x;
  if (idx>=KDIM*KDIM) return;
  int r=idx/KDIM, c=idx%KDIM;
  double v = (c<=r)? scal[r%5]*G2[idx] : 0.0;
  lext[idx]=(float)v;
}

// ---- 32x32 GEMMs, 2x2 per thread, fp64 accumulate ----
// C(f32 MxN) = A(f32 MxK) @ B(f32 KxN)
__global__ __launch_bounds__(256) void gemm32_nn_f(const float* __restrict__ A,const float* __restrict__ B,
                                                   float* __restrict__ C,int M,int N,int K){
  __shared__ float As[GBM][GBK+1], Bs[GBK][GBM+1];
  int tx=threadIdx.x, ty=threadIdx.y;
  int lin=ty*16+tx;
  int m0=blockIdx.y*GBM, n0=blockIdx.x*GBM;
  double a00=0,a01=0,a10=0,a11=0;
  for (int k0=0;k0<K;k0+=GBK){
    for (int e=lin;e<GBM*GBK;e+=256){int r=e/GBK,k=e%GBK;As[r][k]=A[(size_t)(m0+r)*K+k0+k];}
    for (int e=lin;e<GBK*GBM;e+=256){int k=e/GBM,c=e%GBM;Bs[k][c]=B[(size_t)(k0+k)*N+n0+c];}
    __syncthreads();
    #pragma unroll
    for (int t=0;t<GBK;t++){
      double av0=As[2*ty][t], av1=As[2*ty+1][t];
      double bv0=Bs[t][2*tx], bv1=Bs[t][2*tx+1];
      a00+=av0*bv0; a01+=av0*bv1; a10+=av1*bv0; a11+=av1*bv1;
    }
    __syncthreads();
  }
  C[(size_t)(m0+2*ty)*N+n0+2*tx]=(float)a00;
  C[(size_t)(m0+2*ty)*N+n0+2*tx+1]=(float)a01;
  C[(size_t)(m0+2*ty+1)*N+n0+2*tx]=(float)a10;
  C[(size_t)(m0+2*ty+1)*N+n0+2*tx+1]=(float)a11;
}

// C(fp64 MxN) = A(f32 MxK) @ B(f32 NxK)^T
__global__ __launch_bounds__(256) void gemm32_nt_d(const float* __restrict__ A,const float* __restrict__ B,
                                                   double* __restrict__ C,int M,int N,int K){
  __shared__ float As[GBM][GBK+1], Bs[GBM][GBK+1];
  int tx=threadIdx.x, ty=threadIdx.y;
  int lin=ty*16+tx;
  int m0=blockIdx.y*GBM, n0=blockIdx.x*GBM;
  double a00=0,a01=0,a10=0,a11=0;
  for (int k0=0;k0<K;k0+=GBK){
    for (int e=lin;e<GBM*GBK;e+=256){
      int r=e/GBK,k=e%GBK;
      As[r][k]=A[(size_t)(m0+r)*K+k0+k];
      Bs[r][k]=B[(size_t)(n0+r)*K+k0+k];
    }
    __syncthreads();
    #pragma unroll
    for (int t=0;t<GBK;t++){
      double av0=As[2*ty][t], av1=As[2*ty+1][t];
      double bv0=Bs[2*tx][t], bv1=Bs[2*tx+1][t];
      a00+=av0*bv0; a01+=av0*bv1; a10+=av1*bv0; a11+=av1*bv1;
    }
    __syncthreads();
  }
  C[(size_t)(m0+2*ty)*N+n0+2*tx]=a00;
  C[(size_t)(m0+2*ty)*N+n0+2*tx+1]=a01;
  C[(size_t)(m0+2*ty+1)*N+n0+2*tx]=a10;
  C[(size_t)(m0+2*ty+1)*N+n0+2*tx+1]=a11;
}

// C(fp64 MxN, ldc) -= A(fp64 MxK, lda) @ B(fp64 KxN, ldb)
__global__ __launch_bounds__(256) void gemm32_nn_sub_d(const double* __restrict__ A,int lda,
                                                       const double* __restrict__ B,int ldb,
                                                       double* __restrict__ C,int ldc,int M,int N,int K){
  __shared__ double As[GBM][GBK+1], Bs[GBK][GBM+1];
  int tx=threadIdx.x, ty=threadIdx.y;
  int lin=ty*16+tx;
  int m0=blockIdx.y*GBM, n0=blockIdx.x*GBM;
  double a00=0,a01=0,a10=0,a11=0;
  for (int k0=0;k0<K;k0+=GBK){
    for (int e=lin;e<GBM*GBK;e+=256){int r=e/GBK,k=e%GBK;As[r][k]=A[(size_t)(m0+r)*lda+k0+k];}
    for (int e=lin;e<GBK*GBM;e+=256){int k=e/GBM,c=e%GBM;Bs[k][c]=B[(size_t)(k0+k)*ldb+n0+c];}
    __syncthreads();
    #pragma unroll
    for (int t=0;t<GBK;t++){
      double av0=As[2*ty][t], av1=As[2*ty+1][t];
      double bv0=Bs[t][2*tx], bv1=Bs[t][2*tx+1];
      a00+=av0*bv0; a01+=av0*bv1; a10+=av1*bv0; a11+=av1*bv1;
    }
    __syncthreads();
  }
  size_t i00=(size_t)(m0+2*ty)*ldc+n0+2*tx;
  size_t i10=(size_t)(m0+2*ty+1)*ldc+n0+2*tx;
  C[i00]-=a00; C[i00+1]-=a01; C[i10]-=a10; C[i10+1]-=a11;
}

// C(fp64 MxN, ldc) -= A^T @ B, where A is (K x M, lda), B (K x N, ldb)
__global__ __launch_bounds__(256) void gemm32_tn_sub_d(const double* __restrict__ A,int lda,
                                                       const double* __restrict__ B,int ldb,
                                                       double* __restrict__ C,int ldc,int M,int N,int K){
  __shared__ double As[GBK][GBM+1], Bs[GBK][GBM+1];
  int tx=threadIdx.x, ty=threadIdx.y;
  int lin=ty*16+tx;
  int m0=blockIdx.y*GBM, n0=blockIdx.x*GBM;
  double a00=0,a01=0,a10=0,a11=0;
  for (int k0=0;k0<K;k0+=GBK){
    for (int e=lin;e<GBK*GBM;e+=256){
      int k=e/GBM,c=e%GBM;
      As[k][c]=A[(size_t)(k0+k)*lda+m0+c];
      Bs[k][c]=B[(size_t)(k0+k)*ldb+n0+c];
    }
    __syncthreads();
    #pragma unroll
    for (int t=0;t<GBK;t++){
      double av0=As[t][2*ty], av1=As[t][2*ty+1];
      double bv0=Bs[t][2*tx], bv1=Bs[t][2*tx+1];
      a00+=av0*bv0; a01+=av0*bv1; a10+=av1*bv0; a11+=av1*bv1;
    }
    __syncthreads();
  }
  size_t i00=(size_t)(m0+2*ty)*ldc+n0+2*tx;
  size_t i10=(size_t)(m0+2*ty+1)*ldc+n0+2*tx;
  C[i00]-=a00; C[i00+1]-=a01; C[i10]-=a10; C[i10+1]-=a11;
}

// ---- multi-RHS blocked triangular solves: Z = L^{-1} Z then L^{-T} Z ----
__global__ __launch_bounds__(256) void trsm_fwd(const double* __restrict__ L,int n,int b0,
                                                double* __restrict__ Z,int ldz){
  __shared__ double Ls[NB][NB+1];
  __shared__ double rec[NB];
  int lin=threadIdx.x;
  for (int e=lin;e<NB*NB;e+=256){int r=e/NB,c=e%NB;Ls[r][c]=L[(size_t)(b0+r)*n+b0+c];}
  __syncthreads();
  if (lin<NB) rec[lin]=1.0/Ls[lin][lin];
  __syncthreads();
  int col=blockIdx.x*256+lin;
  double z[NB];
  #pragma unroll
  for (int r=0;r<NB;r++) z[r]=Z[(size_t)(b0+r)*ldz+col];
  #pragma unroll
  for (int r=0;r<NB;r++){
    double s=z[r];
    #pragma unroll
    for (int t=0;t<r;t++) s -= Ls[r][t]*z[t];
    z[r]=s*rec[r];
  }
  #pragma unroll
  for (int r=0;r<NB;r++) Z[(size_t)(b0+r)*ldz+col]=z[r];
}

__global__ __launch_bounds__(256) void trsm_bwd(const double* __restrict__ L,int n,int b0,
                                                double* __restrict__ Z,int ldz){
  __shared__ double Ls[NB][NB+1];
  __shared__ double rec[NB];
  int lin=threadIdx.x;
  for (int e=lin;e<NB*NB;e+=256){int r=e/NB,c=e%NB;Ls[r][c]=L[(size_t)(b0+r)*n+b0+c];}
  __syncthreads();
  if (lin<NB) rec[lin]=1.0/Ls[lin][lin];
  __syncthreads();
  int col=blockIdx.x*256+lin;
  double z[NB];
  #pragma unroll
  for (int r=0;r<NB;r++) z[r]=Z[(size_t)(b0+r)*ldz+col];
  #pragma unroll
  for (int ri=NB-1;ri>=0;ri--){
    double s=z[ri];
    #pragma unroll
    for (int t=ri+1;t<NB;t++) s -= Ls[t][ri]*z[t];
    z[ri]=s*rec[ri];
  }
  #pragma unroll
  for (int r=0;r<NB;r++) Z[(size_t)(b0+r)*ldz+col]=z[r];
}

// m_cor = m_ext - Z^T @ m_obs; also u
__global__ void k_mcor(const double* Z, const double* mobs, const double* mext, float* out){
  __shared__ double mo[DDIM];
  for (int s=threadIdx.x;s<DDIM;s+=256) mo[s]=mobs[s];
  __syncthreads();
  int r=blockIdx.x*256+threadIdx.x;
  if (r>=KDIM) return;
  double acc=0;
  for (int s=0;s<DDIM;s++) acc += Z[(size_t)s*KDIM+r]*mo[s];
  double mc = mext[r]-acc;
  out[r]=(float)mc;
  if (r%5==0) out[OUT_U + r/5]=(float)mc;
}

// l_cor = l_ext - Z^T @ l_obs_ns
__global__ __launch_bounds__(256) void k_lcor(const double* __restrict__ Z, const float* __restrict__ lobs,
                                              const float* __restrict__ lext, float* __restrict__ out){
  __shared__ double As[GBK][GBM+1];
  __shared__ float  Bs[GBK][GBM+1];
  int tx=threadIdx.x, ty=threadIdx.y;
  int lin=ty*16+tx;
  int m0=blockIdx.y*GBM, n0=blockIdx.x*GBM;
  double a00=0,a01=0,a10=0,a11=0;
  for (int s0=0;s0<DDIM;s0+=GBK){
    for (int e=lin;e<GBK*GBM;e+=256){
      int k=e/GBM,c=e%GBM;
      As[k][c]=Z[(size_t)(s0+k)*KDIM+m0+c];
      Bs[k][c]=lobs[(size_t)(s0+k)*KDIM+n0+c];
    }
    __syncthreads();
    #pragma unroll
    for (int t=0;t<GBK;t++){
      double av0=As[t][2*ty], av1=As[t][2*ty+1];
      double bv0=Bs[t][2*tx], bv1=Bs[t][2*tx+1];
      a00+=av0*bv0; a01+=av0*bv1; a10+=av1*bv0; a11+=av1*bv1;
    }
    __syncthreads();
  }
  size_t r0=(size_t)(m0+2*ty)*KDIM+n0+2*tx;
  size_t r1=(size_t)(m0+2*ty+1)*KDIM+n0+2*tx;
  out[OUT_LCOR+r0]  =(float)((double)lext[r0]  -a00);
  out[OUT_LCOR+r0+1]=(float)((double)lext[r0+1]-a01);
  out[OUT_LCOR+r1]  =(float)((double)lext[r1]  -a10);
  out[OUT_LCOR+r1+1]=(float)((double)lext[r1+1]-a11);
}

extern "C" void kernel_launch(void* const* d_in, const int* in_sizes, int n_in,
                              void* d_out, int out_size, void* d_ws, size_t ws_size,
                              hipStream_t stream) {
  const float* m0  = (const float*)d_in[0];
  const float* l0  = (const float*)d_in[1];
  const float* H   = (const float*)d_in[2];
  const float* bias= (const float*)d_in[3];
  const float* dt  = (const float*)d_in[4];
  const float* a   = (const float*)d_in[5];
  const float* q   = (const float*)d_in[6];
  float* out = (float*)d_out;

  char* w=(char*)d_ws;
  auto alloc=[&](size_t bytes)->char*{ char* p=w; w += ((bytes+255)/256)*256; return p; };
  double* scal =(double*)alloc(16*8);
  double* mext =(double*)alloc((size_t)KDIM*8);
  double* mobs =(double*)alloc((size_t)DDIM*8);
  double* g1d  =(double*)alloc((size_t)DDIM*8);
  double* betaA=(double*)alloc((size_t)QN*8);
  double* vheadA=(double*)alloc((size_t)QN*8);
  double* Tbuf =(double*)alloc((size_t)PW*PW*8);
  double* W2   =(double*)alloc((size_t)QN*PW*8);
  double* Aq   =(double*)alloc((size_t)QM*QN*8);     // QR working matrix (fp64)
  double* Rq   =(double*)alloc((size_t)QN*QN*8);     // R factor
  double* S    =(double*)alloc((size_t)DDIM*DDIM*8); // innovation Gram + chol
  double* G2   =(double*)alloc((size_t)KDIM*KDIM*8); // big Gram -> chol; reused as Z
  float*  LOBS =(float*) alloc((size_t)DDIM*KDIM*4);
  float*  X    =(float*) alloc((size_t)KDIM*KDIM*4); // X; later l_ext
  double* Z    = G2;       // fp64 DDIM x KDIM, alias after k_extract
  float*  LEXT = X;

  dim3 t16(16,16);

  // ---- extrapolate mean, observe ----
  k_setup<<<1,1,0,stream>>>(dt, scal);
  k_mext<<<(KDIM+255)/256,256,0,stream>>>(a, m0, scal, mext);
  k_mobs<<<DDIM,256,0,stream>>>(H, bias, mext, mobs);

  // ---- first QR: Householder fp64, LAPACK signs ----
  k_A<<<(QN*QM+255)/256,256,0,stream>>>(H, q, scal, Aq);
  for (int p=0;p<QN/PW;p++){
    int col0=p*PW;
    qr_panel<<<1,1024,0,stream>>>(Aq, betaA, vheadA, col0);
    int ntr = QN - col0 - PW;
    if (ntr>0){
      qr_vtvT<<<1,512,0,stream>>>(Aq,betaA,vheadA,col0,Tbuf);
      int rowchunks = (QM - col0 + 255)/256;
      qr_w1<<<ntr,256,0,stream>>>(Aq,vheadA,Tbuf,col0,W2);
      qr_apply<<<dim3(ntr,rowchunks),256,0,stream>>>(Aq,vheadA,W2,col0);
    }
  }
  k_extractR<<<(QN*QN+255)/256,256,0,stream>>>(Aq, Rq);
  k_colnorm<<<(QN+255)/256,256,0,stream>>>(Rq, g1d);
  k_resw<<<1,DDIM,0,stream>>>(Rq, mobs, g1d, scal, out);

  // ---- extrapolated covariance sqrt via Gram + Cholesky ----
  k_X<<<(KDIM*KDIM+255)/256,256,0,stream>>>(a, l0, scal, X);
  syrk_lower<<<dim3(KDIM/GBM,KDIM/GBM),t16,0,stream>>>(X, G2, KDIM);
  k_addqqt<<<(DDIM*15+255)/256,256,0,stream>>>(q, scal, G2);
  chol_blocked(G2, KDIM, stream);
  k_extract<<<(KDIM*KDIM+255)/256,256,0,stream>>>(G2, scal, LEXT);  // X region now l_ext; G2 dead -> Z

  // ---- correction ----
  gemm32_nn_f<<<dim3(KDIM/GBM,DDIM/GBM),t16,0,stream>>>(H, LEXT, LOBS, DDIM, KDIM, KDIM);
  gemm32_nt_d<<<dim3(DDIM/GBM,DDIM/GBM),t16,0,stream>>>(LOBS, LOBS, S, DDIM, DDIM, KDIM);
  chol_blocked(S, DDIM, stream);
  // Z = LOBS @ LEXT^T  (= crosscov^T), fp64
  gemm32_nt_d<<<dim3(KDIM/GBM,DDIM/GBM),t16,0,stream>>>(LOBS, LEXT, Z, DDIM, KDIM, KDIM);
  // cho_solve: Z <- L^{-1} Z ; Z <- L^{-T} Z  (then gain = Z^T)
  for (int b=0;b<DDIM;b+=NB){
    trsm_fwd<<<KDIM/256,256,0,stream>>>(S, DDIM, b, Z, KDIM);
    int m = DDIM-b-NB;
    if (m>0)
      gemm32_nn_sub_d<<<dim3(KDIM/GBM,m/GBM),t16,0,stream>>>(
        S+(size_t)(b+NB)*DDIM+b, DDIM, Z+(size_t)b*KDIM, KDIM,
        Z+(size_t)(b+NB)*KDIM, KDIM, m, KDIM, NB);
  }
  for (int b=DDIM-NB;b>=0;b-=NB){
    trsm_bwd<<<KDIM/256,256,0,stream>>>(S, DDIM, b, Z, KDIM);
    if (b>0)
      gemm32_tn_sub_d<<<dim3(KDIM/GBM,b/GBM),t16,0,stream>>>(
        S+(size_t)b*DDIM, DDIM, Z+(size_t)b*KDIM, KDIM,
        Z, KDIM, b, KDIM, NB);
  }

  k_mcor<<<(KDIM+255)/256,256,0,stream>>>(Z, mobs, mext, out);
  k_lcor<<<dim3(KDIM/GBM,KDIM/GBM),t16,0,stream>>>(Z, LOBS, LEXT, out);
}